// Round 19
// baseline (256.283 us; speedup 1.0000x reference)
//
#include <hip/hip_runtime.h>
#include <hip/hip_bf16.h>

#define S 2048
#define B 2
#define D 2048
#define H 16
#define HD 128
#define N3 6144   // 3*D
#define KD 2048   // GEMM K dim

typedef __hip_bfloat16 bf16;
typedef float f32x4 __attribute__((ext_vector_type(4)));
typedef short short8 __attribute__((ext_vector_type(8)));
typedef short sv4 __attribute__((ext_vector_type(4)));

__device__ __forceinline__ void gload16(const void* g, void* l) {
    __builtin_amdgcn_global_load_lds((const __attribute__((address_space(1))) void*)g,
                                     (__attribute__((address_space(3))) void*)l, 16, 0, 0);
}
__device__ __forceinline__ void bar() {
    asm volatile("" ::: "memory");
    __builtin_amdgcn_s_barrier();
    asm volatile("" ::: "memory");
}

__device__ __forceinline__ short8 cvt8(const float* p) {
    f32x4 a = *(const f32x4*)p;
    f32x4 b = *(const f32x4*)(p + 4);
    short8 r;
#pragma unroll
    for (int j = 0; j < 4; ++j) {
        __hip_bfloat16 t0 = __float2bfloat16(a[j]);
        __hip_bfloat16 t1 = __float2bfloat16(b[j]);
        r[j]     = reinterpret_cast<short&>(t0);
        r[j + 4] = reinterpret_cast<short&>(t1);
    }
    return r;
}

// ---------------- convert kernels (vectorized: float4 x2 -> short8) ----------------
__global__ __launch_bounds__(256) void cvt_x_kernel(const float* __restrict__ x, bf16* __restrict__ xb) {
    int i = (blockIdx.x * 256 + threadIdx.x) * 8;   // over [S][B][D], 8 consec d
    int d  = i & (D - 1);
    int sb = i >> 11;        // s*B + b
    int b  = sb & (B - 1);
    int s  = sb >> 1;
    *(short8*)&xb[((size_t)(b * S + s) << 11) + d] = cvt8(x + i);
}

__global__ __launch_bounds__(256) void cvt_w_kernel(const float* __restrict__ in, bf16* __restrict__ o, int n) {
    for (int i = (blockIdx.x * blockDim.x + threadIdx.x) * 8; i < n; i += gridDim.x * blockDim.x * 8)
        *(short8*)&o[i] = cvt8(in + i);
}

// ---------------- 128x128 GEMM, BK=64, DOUBLE-buffer + whole-tile reg fragments, 1 barrier/tile ----------------
// Per K-tile: stage T+1 into buf^1 (earliest DMA issue; buf^1's tile t-1 was fully
// consumed before the previous barrier) -> ds_read ALL frags from buf to regs ->
// MFMA (per-wave lgkm waits) -> vmcnt(0) (slack = reads+MFMA) -> ONE barrier.
// Removes R15's mid lgkmcnt(0)+barrier pair.  LDS 64KB/block -> 2 blocks/CU.
// L2-aware rasterization: each XCD owns a contiguous N-slice; M walks inside.
// NOTE (R16 lesson): 256x128 wave-tile spills — 64x64 wave tile is the stable point.
// NOTE (R18 lesson): launch_bounds(256,3) is a no-op; residency not the limiter.
template <int MODE>
__global__ __launch_bounds__(256, 2) void gemm128(
    const bf16* __restrict__ A, const bf16* __restrict__ W, const float* __restrict__ bias,
    bf16* __restrict__ oq, bf16* __restrict__ ok, bf16* __restrict__ ovT,
    float* __restrict__ oOut)
{
    constexpr int NT = KD / 64;    // 32 K-tiles

    __shared__ __align__(16) bf16 SA[2][128 * 64];
    __shared__ __align__(16) bf16 SB[2][128 * 64];

    const int tid = threadIdx.x;
    const int w = tid >> 6, l = tid & 63;
    const int wm = w >> 1, wn = w & 1;
    const int l15 = l & 15, l4 = l >> 4;

    const int id  = blockIdx.y * gridDim.x + blockIdx.x;
    const int xcd = id & 7;
    const int j   = id >> 3;                 // 0..nwg/8-1
    const int npx = gridDim.x >> 3;          // N-tiles per XCD (6 for QKV, 2 for WO)
    const int tileN = (xcd * npx + j % npx) * 128;
    const int tileM = (j / npx) * 128;

    const int lrow8 = l >> 3;                                // 0..7 == row&7
    const int lsb   = ((l & 7) * 16) ^ (lrow8 << 4);         // byte within 128B row-seg
    const int rxor  = (l15 & 7) << 3;

    const char* AgT = (const char*)A + (size_t)tileM * (KD * 2);
    const char* WgT = (const char*)W + (size_t)tileN * (KD * 2);

    auto stage_tile = [&](int buf, int kt) {
#pragma unroll
        for (int j2 = 0; j2 < 4; ++j2) {
            const int chunk = w * 4 + j2;                    // 0..15 -> 128 rows
            gload16(AgT + (size_t)(chunk * 8 + lrow8) * (KD * 2) + kt * 128 + lsb,
                    (char*)&SA[buf][0] + chunk * 1024);
        }
#pragma unroll
        for (int j2 = 0; j2 < 4; ++j2) {
            const int chunk = w * 4 + j2;
            gload16(WgT + (size_t)(chunk * 8 + lrow8) * (KD * 2) + kt * 128 + lsb,
                    (char*)&SB[buf][0] + chunk * 1024);
        }
    };

    f32x4 acc[4][4] = {};

    // prologue: stage tile 0 into buf0
    stage_tile(0, 0);
    asm volatile("s_waitcnt vmcnt(0)" ::: "memory");
    bar();

#pragma unroll 1
    for (int t = 0; t < NT; ++t) {
        const int cur = t & 1;
        // 1) stage next tile into the OTHER buffer (its old tile was consumed by
        //    every wave before the previous barrier -> safe; earliest DMA issue)
        if (t + 1 < NT) stage_tile(cur ^ 1, t + 1);

        // 2) whole-tile fragment loads to registers from buf[cur]
        short8 bfrag[2][4], afr[2][4];
#pragma unroll
        for (int kk = 0; kk < 2; ++kk) {
#pragma unroll
            for (int ni = 0; ni < 4; ++ni)
                bfrag[kk][ni] = *(const short8*)&SB[cur][(wn * 64 + ni * 16 + l15) * 64 +
                                                        ((kk * 32 + l4 * 8) ^ rxor)];
#pragma unroll
            for (int q = 0; q < 4; ++q)
                afr[kk][q] = *(const short8*)&SA[cur][(wm * 64 + q * 16 + l15) * 64 +
                                                     ((kk * 32 + l4 * 8) ^ rxor)];
        }

        // 3) MFMA from registers (compiler inserts fine-grained lgkm waits)
        __builtin_amdgcn_s_setprio(1);
#pragma unroll
        for (int kk = 0; kk < 2; ++kk)
#pragma unroll
            for (int q = 0; q < 4; ++q)
#pragma unroll
                for (int ni = 0; ni < 4; ++ni)
                    acc[q][ni] = __builtin_amdgcn_mfma_f32_16x16x32_bf16(
                        afr[kk][q], bfrag[kk][ni], acc[q][ni], 0, 0, 0);
        __builtin_amdgcn_s_setprio(0);

        // 4) next tile landed (slack = reads + whole MFMA block); single barrier
        asm volatile("s_waitcnt vmcnt(0)" ::: "memory");
        bar();
    }

    // epilogue
#pragma unroll
    for (int mi = 0; mi < 4; ++mi) {
#pragma unroll
        for (int ni = 0; ni < 4; ++ni) {
            const int ncol = tileN + wn * 64 + ni * 16 + l15;
            const float bv = bias[ncol];
            const int m0 = tileM + wm * 64 + mi * 16 + l4 * 4;
            if (MODE == 0) {
                const int b_ = m0 >> 11, s0 = m0 & (S - 1);
                const int which = ncol >> 11;
                const int hh = (ncol >> 7) & (H - 1);
                const int hd = ncol & (HD - 1);
                const int bh = b_ * H + hh;
                if (which == 2) {
                    sv4 pk;
#pragma unroll
                    for (int r = 0; r < 4; ++r) {
                        __hip_bfloat16 t = __float2bfloat16(acc[mi][ni][r] + bv);
                        pk[r] = reinterpret_cast<short&>(t);
                    }
                    *(sv4*)&ovT[((size_t)bh * HD + hd) * S + s0] = pk;
                } else {
                    bf16* dst = which ? ok : oq;
#pragma unroll
                    for (int r = 0; r < 4; ++r)
                        dst[((size_t)bh * S + s0 + r) * HD + hd] =
                            __float2bfloat16(acc[mi][ni][r] + bv);
                }
            } else {
#pragma unroll
                for (int r = 0; r < 4; ++r) {
                    const int m = m0 + r;
                    const int b_ = m >> 11, s_ = m & (S - 1);
                    oOut[((size_t)s_ * B + b_) * D + ncol] = acc[mi][ni][r] + bv;
                }
            }
        }
    }
}

// ---------------- fused LayerNorm (over HD) + RoPE for q and k, in place ----------------
// q is additionally pre-scaled by 1/sqrt(HD) (folded out of the attention kernel).
__global__ __launch_bounds__(256) void ln_rope_kernel(
    bf16* __restrict__ q, bf16* __restrict__ k,
    const float* __restrict__ fc,
    const float* __restrict__ qw, const float* __restrict__ qb,
    const float* __restrict__ kw, const float* __restrict__ kb)
{
    const int tid = threadIdx.x;
    const int w = tid >> 6, l = tid & 63;
    const int row = blockIdx.x * 4 + w;      // bh*S + s, 0..65535
    const int s_ = row & (S - 1);
    const size_t base = (size_t)row * HD;
    const float f0 = fc[s_ * HD + 2 * l];
    const float f1 = fc[s_ * HD + 2 * l + 1];

#pragma unroll
    for (int which = 0; which < 2; ++which) {
        bf16* p = which == 0 ? q : k;
        const float* gw = which == 0 ? qw : kw;
        const float* gb = which == 0 ? qb : kb;
        const float osc = which == 0 ? 0.08838834764831845f : 1.0f;  // 1/sqrt(128) on q
        float x0 = __bfloat162float(p[base + 2 * l]);
        float x1 = __bfloat162float(p[base + 2 * l + 1]);
        float sm = x0 + x1;
#pragma unroll
        for (int msk = 1; msk < 64; msk <<= 1) sm += __shfl_xor(sm, msk);
        const float mu = sm * (1.0f / HD);
        const float d0 = x0 - mu, d1 = x1 - mu;
        float vs = d0 * d0 + d1 * d1;
#pragma unroll
        for (int msk = 1; msk < 64; msk <<= 1) vs += __shfl_xor(vs, msk);
        const float rstd = rsqrtf(vs * (1.0f / HD) + 1e-5f);
        const float n0 = d0 * rstd * gw[2 * l] + gb[2 * l];
        const float n1 = d1 * rstd * gw[2 * l + 1] + gb[2 * l + 1];
        p[base + 2 * l]     = __float2bfloat16((n0 * f0 - n1 * f1) * osc);
        p[base + 2 * l + 1] = __float2bfloat16((n1 * f0 + n0 * f1) * osc);
    }
}

// ---------------- causal flash attention: dual-Q pairing + fixed-shift softmax ----------------
// 512 blocks (2/CU exactly): block owns q-tiles (31-pr) and (pr) of one head -> every
// block does exactly 33 tile-works (perfect balance). K/V tiles staged ONCE serve both
// q-tiles over their overlapping KV range. Counted-vmcnt pipeline, K/V double-buffered.
// Per-q-tile QK^T/softmax kept SEQUENTIAL with scoped sacc (merged version spills regs).
__global__ __launch_bounds__(256, 2) void attn_kernel(
    const bf16* __restrict__ q, const bf16* __restrict__ k, const bf16* __restrict__ vT,
    bf16* __restrict__ out)
{
    __shared__ __align__(16) bf16 KT[2][64 * 128];   // 2 x 16 KB
    __shared__ __align__(16) bf16 VS[2][128 * 64];   // 2 x 16 KB
    __shared__ __align__(16) bf16 Pb[4][16 * 72];    // per-wave P transpose (A then B, sequential)

    const int tid = threadIdx.x, w = tid >> 6, l = tid & 63;
    const int l15 = l & 15, l4 = l >> 4;

    const int id  = blockIdx.y * gridDim.x + blockIdx.x;   // 0..511
    const int nid = (id & 7) * 64 + (id >> 3);             // XCD-chunked (512 % 8 == 0)
    const int bh  = nid >> 4;                               // 0..31
    const int pr  = nid & 15;                               // 0..15
    const int qtA = 31 - pr;                                // heavy q-tile (16..31)
    const int qtB = pr;                                     // light q-tile (0..15)

    const int b_ = bh >> 4, hh = bh & (H - 1);
    const int qrA = qtA * 64 + w * 16;
    const int qrB = qtB * 64 + w * 16;
    const size_t hQ = (size_t)bh * S * HD;
    const size_t hV = (size_t)bh * HD * S;

    const char* kbase = (const char*)(k + hQ);
    const char* vbase = (const char*)(vT + hV);
    int ksrc[4], vsrc[4], kdst[4], vdst[4];
#pragma unroll
    for (int j = 0; j < 4; ++j) {
        const int ik = w * 4 + j;
        const int rt = ik * 4 + (l >> 4);            // K tile row 0..63
        ksrc[j] = rt * 256 + (((l & 15) * 16) ^ ((rt & 15) << 4));
        kdst[j] = ik * 1024;
        const int rd = ik * 8 + (l >> 3);            // V tile row (d) 0..127
        vsrc[j] = rd * (S * 2) + (((l & 7) * 16) ^ ((rd & 7) << 4));
        vdst[j] = ik * 1024;
    }

    short8 aqA[4], aqB[4];
#pragma unroll
    for (int c = 0; c < 4; ++c) {
        aqA[c] = *(const short8*)&q[hQ + (size_t)(qrA + l15) * HD + c * 32 + l4 * 8];
        aqB[c] = *(const short8*)&q[hQ + (size_t)(qrB + l15) * HD + c * 32 + l4 * 8];
    }

    f32x4 oA[8] = {}, oB[8] = {};
    float psA[4] = {0.f, 0.f, 0.f, 0.f}, psB[4] = {0.f, 0.f, 0.f, 0.f};

    // prologue: issue K tile 0 (first iter's vmcnt covers it)
#pragma unroll
    for (int j = 0; j < 4; ++j)
        gload16(kbase + ksrc[j], (char*)KT[0] + kdst[j]);

    const int kx = l15 << 3;          // K read xor (elems): (row&15)<<3
    const int vx = (l15 & 7) << 3;    // V read xor (elems): (row&7)<<3
    const float LOG2E = 1.4426950408889634f;
    const float SHIFT = -23.083120654223414f;   // -16 * log2(e)

    for (int kvt = 0; kvt <= qtA; ++kvt) {
        const int kvb = kvt * 64;
        const int cur = kvt & 1;
        const bool doB = (kvt <= qtB);
        // issue V_t FIRST (pre-PV vmcnt(4) then leaves only K_{t+1} in flight)
#pragma unroll
        for (int j = 0; j < 4; ++j)
            gload16(vbase + (size_t)kvb * 2 + vsrc[j], (char*)VS[cur] + vdst[j]);
        if (kvt < qtA) {
#pragma unroll
            for (int j = 0; j < 4; ++j)
                gload16(kbase + (size_t)(kvb + 64) * 256 + ksrc[j], (char*)KT[cur ^ 1] + kdst[j]);
        }
        // K_t landed for every wave; V_t (+K_{t+1}) stay in flight
        if (kvt < qtA) { asm volatile("s_waitcnt vmcnt(8)" ::: "memory"); }
        else           { asm volatile("s_waitcnt vmcnt(4)" ::: "memory"); }
        bar();

        // ---- q-tile A: QK^T + fixed-shift softmax + P transpose (scoped sacc) ----
        short8 apA[2], apB[2];
        {
            f32x4 sacc[4] = {};
#pragma unroll
            for (int c = 0; c < 4; ++c) {
                const int cole = (c * 32 + l4 * 8) ^ kx;
#pragma unroll
                for (int n = 0; n < 4; ++n) {
                    short8 bk = *(const short8*)&KT[cur][(n * 16 + l15) * 128 + cole];
                    sacc[n] = __builtin_amdgcn_mfma_f32_16x16x32_bf16(aqA[c], bk, sacc[n], 0, 0, 0);
                }
            }
            if (kvt == qtA) {
#pragma unroll
                for (int n = 0; n < 4; ++n)
#pragma unroll
                    for (int r = 0; r < 4; ++r) {
                        float sv = (kvb + n * 16 + l15 > qrA + l4 * 4 + r) ? -1e30f : sacc[n][r];
                        const float pv = __builtin_amdgcn_exp2f(__builtin_fmaf(sv, LOG2E, SHIFT));
                        sacc[n][r] = pv; psA[r] += pv;
                    }
            } else {
#pragma unroll
                for (int n = 0; n < 4; ++n)
#pragma unroll
                    for (int r = 0; r < 4; ++r) {
                        const float pv = __builtin_amdgcn_exp2f(__builtin_fmaf(sacc[n][r], LOG2E, SHIFT));
                        sacc[n][r] = pv; psA[r] += pv;
                    }
            }
#pragma unroll
            for (int n = 0; n < 4; ++n)
#pragma unroll
                for (int r = 0; r < 4; ++r)
                    Pb[w][(l4 * 4 + r) * 72 + n * 16 + l15] = __float2bfloat16(sacc[n][r]);
#pragma unroll
            for (int c = 0; c < 2; ++c)
                apA[c] = *(const short8*)&Pb[w][l15 * 72 + c * 32 + l4 * 8];
        }
        // ---- q-tile B (shares KT[cur]; same-wave sequential Pb reuse) ----
        if (doB) {
            f32x4 sacc[4] = {};
#pragma unroll
            for (int c = 0; c < 4; ++c) {
                const int cole = (c * 32 + l4 * 8) ^ kx;
#pragma unroll
                for (int n = 0; n < 4; ++n) {
                    short8 bk = *(const short8*)&KT[cur][(n * 16 + l15) * 128 + cole];
                    sacc[n] = __builtin_amdgcn_mfma_f32_16x16x32_bf16(aqB[c], bk, sacc[n], 0, 0, 0);
                }
            }
            if (kvt == qtB) {
#pragma unroll
                for (int n = 0; n < 4; ++n)
#pragma unroll
                    for (int r = 0; r < 4; ++r) {
                        float sv = (kvb + n * 16 + l15 > qrB + l4 * 4 + r) ? -1e30f : sacc[n][r];
                        const float pv = __builtin_amdgcn_exp2f(__builtin_fmaf(sv, LOG2E, SHIFT));
                        sacc[n][r] = pv; psB[r] += pv;
                    }
            } else {
#pragma unroll
                for (int n = 0; n < 4; ++n)
#pragma unroll
                    for (int r = 0; r < 4; ++r) {
                        const float pv = __builtin_amdgcn_exp2f(__builtin_fmaf(sacc[n][r], LOG2E, SHIFT));
                        sacc[n][r] = pv; psB[r] += pv;
                    }
            }
#pragma unroll
            for (int n = 0; n < 4; ++n)
#pragma unroll
                for (int r = 0; r < 4; ++r)
                    Pb[w][(l4 * 4 + r) * 72 + n * 16 + l15] = __float2bfloat16(sacc[n][r]);
#pragma unroll
            for (int c = 0; c < 2; ++c)
                apB[c] = *(const short8*)&Pb[w][l15 * 72 + c * 32 + l4 * 8];
        }

        // V_t landed for every wave; K_{t+1} stays in flight
        if (kvt < qtA) { asm volatile("s_waitcnt vmcnt(4)" ::: "memory"); }
        else           { asm volatile("s_waitcnt vmcnt(0)" ::: "memory"); }
        bar();

#pragma unroll
        for (int c = 0; c < 2; ++c) {
#pragma unroll
            for (int d = 0; d < 8; ++d) {
                const int rd = d * 16 + l15;
                short8 bv = *(const short8*)&VS[cur][rd * 64 + ((c * 32 + l4 * 8) ^ vx)];
                oA[d] = __builtin_amdgcn_mfma_f32_16x16x32_bf16(apA[c], bv, oA[d], 0, 0, 0);
            }
        }
        if (doB) {
#pragma unroll
            for (int c = 0; c < 2; ++c) {
#pragma unroll
                for (int d = 0; d < 8; ++d) {
                    const int rd = d * 16 + l15;
                    short8 bv = *(const short8*)&VS[cur][rd * 64 + ((c * 32 + l4 * 8) ^ vx)];
                    oB[d] = __builtin_amdgcn_mfma_f32_16x16x32_bf16(apB[c], bv, oB[d], 0, 0, 0);
                }
            }
        }
        // no end barrier: VS double-buffered; KT[cur^1] overwrite at t+1 is safe
        // (QK^T-t reads completed before this iter's 2nd barrier).
    }

    // epilogue: deferred row-sum reduce, normalize, write bf16 [B,S,D] for both q-tiles
#pragma unroll
    for (int r = 0; r < 4; ++r) {
#pragma unroll
        for (int msk = 1; msk < 16; msk <<= 1) psA[r] += __shfl_xor(psA[r], msk);
        const float inv = 1.0f / psA[r];
        const int s_ = qrA + l4 * 4 + r;
        const size_t obase = ((size_t)b_ * S + s_) * D + hh * HD;
#pragma unroll
        for (int d = 0; d < 8; ++d)
            out[obase + d * 16 + l15] = __float2bfloat16(oA[d][r] * inv);
    }
#pragma unroll
    for (int r = 0; r < 4; ++r) {
#pragma unroll
        for (int msk = 1; msk < 16; msk <<= 1) psB[r] += __shfl_xor(psB[r], msk);
        const float inv = 1.0f / psB[r];
        const int s_ = qrB + l4 * 4 + r;
        const size_t obase = ((size_t)b_ * S + s_) * D + hh * HD;
#pragma unroll
        for (int d = 0; d < 8; ++d)
            out[obase + d * 16 + l15] = __float2bfloat16(oB[d][r] * inv);
    }
}

extern "C" void kernel_launch(void* const* d_in, const int* in_sizes, int n_in,
                              void* d_out, int out_size, void* d_ws, size_t ws_size,
                              hipStream_t stream) {
    const float* x      = (const float*)d_in[0];
    const float* fc     = (const float*)d_in[1];
    const float* wqkv_w = (const float*)d_in[2];
    const float* wqkv_b = (const float*)d_in[3];
    const float* wo_w   = (const float*)d_in[4];
    const float* wo_b   = (const float*)d_in[5];
    const float* qn_w   = (const float*)d_in[6];
    const float* qn_b   = (const float*)d_in[7];
    const float* kn_w   = (const float*)d_in[8];
    const float* kn_b   = (const float*)d_in[9];
    float* out = (float*)d_out;
    char* ws = (char*)d_ws;

    bf16* xb = (bf16*)(ws);                    // [B*S][D]
    bf16* w1 = (bf16*)(ws + 16777216);         // [6144][2048]
    bf16* wo = (bf16*)(ws + 41943040);         // [2048][2048]
    bf16* qb = (bf16*)(ws + 50331648);         // [B][H][S][HD]
    bf16* kb = (bf16*)(ws + 67108864);         // [B][H][S][HD]
    bf16* vT = (bf16*)(ws + 83886080);         // [B][H][HD][S]
    bf16* ao = (bf16*)(ws + 100663296);        // [B*S][D]

    cvt_x_kernel<<<(S * B * D) / (256 * 8), 256, 0, stream>>>(x, xb);
    cvt_w_kernel<<<2048, 256, 0, stream>>>(wqkv_w, w1, N3 * D);
    cvt_w_kernel<<<1024, 256, 0, stream>>>(wo_w, wo, D * D);

    gemm128<0><<<dim3(N3 / 128, (B * S) / 128), 256, 0, stream>>>(
        xb, w1, wqkv_b, qb, kb, vT, nullptr);

    ln_rope_kernel<<<(B * H * S) / 4, 256, 0, stream>>>(qb, kb, fc, qn_w, qn_b, kn_w, kn_b);

    attn_kernel<<<dim3(16, B * H), 256, 0, stream>>>(qb, kb, vT, ao);

    gemm128<1><<<dim3(D / 128, (B * S) / 128), 256, 0, stream>>>(
        ao, wo, wo_b, nullptr, nullptr, nullptr, out);
}

// Round 20
// 230.334 us; speedup vs baseline: 1.1127x; 1.1127x over previous
//
#include <hip/hip_runtime.h>
#include <hip/hip_bf16.h>

#define S 2048
#define B 2
#define D 2048
#define H 16
#define HD 128
#define N3 6144   // 3*D
#define KD 2048   // GEMM K dim

typedef __hip_bfloat16 bf16;
typedef float f32x4 __attribute__((ext_vector_type(4)));
typedef short short8 __attribute__((ext_vector_type(8)));
typedef short sv4 __attribute__((ext_vector_type(4)));

__device__ __forceinline__ void gload16(const void* g, void* l) {
    __builtin_amdgcn_global_load_lds((const __attribute__((address_space(1))) void*)g,
                                     (__attribute__((address_space(3))) void*)l, 16, 0, 0);
}
__device__ __forceinline__ void bar() {
    asm volatile("" ::: "memory");
    __builtin_amdgcn_s_barrier();
    asm volatile("" ::: "memory");
}

__device__ __forceinline__ short8 cvt8(const float* p) {
    f32x4 a = *(const f32x4*)p;
    f32x4 b = *(const f32x4*)(p + 4);
    short8 r;
#pragma unroll
    for (int j = 0; j < 4; ++j) {
        __hip_bfloat16 t0 = __float2bfloat16(a[j]);
        __hip_bfloat16 t1 = __float2bfloat16(b[j]);
        r[j]     = reinterpret_cast<short&>(t0);
        r[j + 4] = reinterpret_cast<short&>(t1);
    }
    return r;
}

// ---------------- convert kernels (vectorized: float4 x2 -> short8) ----------------
__global__ __launch_bounds__(256) void cvt_x_kernel(const float* __restrict__ x, bf16* __restrict__ xb) {
    int i = (blockIdx.x * 256 + threadIdx.x) * 8;   // over [S][B][D], 8 consec d
    int d  = i & (D - 1);
    int sb = i >> 11;        // s*B + b
    int b  = sb & (B - 1);
    int s  = sb >> 1;
    *(short8*)&xb[((size_t)(b * S + s) << 11) + d] = cvt8(x + i);
}

__global__ __launch_bounds__(256) void cvt_w_kernel(const float* __restrict__ in, bf16* __restrict__ o, int n) {
    for (int i = (blockIdx.x * blockDim.x + threadIdx.x) * 8; i < n; i += gridDim.x * blockDim.x * 8)
        *(short8*)&o[i] = cvt8(in + i);
}

// ---------------- 128x128 GEMM, BK=64, SINGLE-buffer + whole-tile reg fragments ----------------
// Per K-tile: ds_read ALL frags to regs -> lgkmcnt(0)+barrier (buffer retired) ->
// stage T+1 into the SAME buffer -> 32 MFMA from regs (hides load latency) ->
// vmcnt(0) (slack = full MFMA block) -> barrier.  LDS 32KB/block.
// L2-aware rasterization: each XCD owns a contiguous N-slice; M walks inside.
// STRUCTURE NOTES (measured): this is the local optimum. Variants all worse/null:
//   R6 per-phase barriers (-10%), R16 256x128 wave tile (VGPR spill, -2x),
//   R18 launch_bounds(,3) (null), R19 dbuf+1-barrier (LDS port contention, -20%).
template <int MODE>
__global__ __launch_bounds__(256, 3) void gemm128(
    const bf16* __restrict__ A, const bf16* __restrict__ W, const float* __restrict__ bias,
    bf16* __restrict__ oq, bf16* __restrict__ ok, bf16* __restrict__ ovT,
    float* __restrict__ oOut)
{
    constexpr int NT = KD / 64;    // 32 K-tiles

    __shared__ __align__(16) bf16 SA[128 * 64];
    __shared__ __align__(16) bf16 SB[128 * 64];

    const int tid = threadIdx.x;
    const int w = tid >> 6, l = tid & 63;
    const int wm = w >> 1, wn = w & 1;
    const int l15 = l & 15, l4 = l >> 4;

    const int id  = blockIdx.y * gridDim.x + blockIdx.x;
    const int xcd = id & 7;
    const int j   = id >> 3;                 // 0..nwg/8-1
    const int npx = gridDim.x >> 3;          // N-tiles per XCD (6 for QKV, 2 for WO)
    const int tileN = (xcd * npx + j % npx) * 128;
    const int tileM = (j / npx) * 128;

    const int lrow8 = l >> 3;                                // 0..7 == row&7
    const int lsb   = ((l & 7) * 16) ^ (lrow8 << 4);         // byte within 128B row-seg
    const int rxor  = (l15 & 7) << 3;

    const char* AgT = (const char*)A + (size_t)tileM * (KD * 2);
    const char* WgT = (const char*)W + (size_t)tileN * (KD * 2);

    auto stage_tile = [&](int kt) {
#pragma unroll
        for (int j2 = 0; j2 < 4; ++j2) {
            const int chunk = w * 4 + j2;                    // 0..15 -> 128 rows
            gload16(AgT + (size_t)(chunk * 8 + lrow8) * (KD * 2) + kt * 128 + lsb,
                    (char*)&SA[0] + chunk * 1024);
        }
#pragma unroll
        for (int j2 = 0; j2 < 4; ++j2) {
            const int chunk = w * 4 + j2;
            gload16(WgT + (size_t)(chunk * 8 + lrow8) * (KD * 2) + kt * 128 + lsb,
                    (char*)&SB[0] + chunk * 1024);
        }
    };

    f32x4 acc[4][4] = {};

    // prologue: stage tile 0
    stage_tile(0);
    asm volatile("s_waitcnt vmcnt(0)" ::: "memory");
    bar();

#pragma unroll 1
    for (int t = 0; t < NT; ++t) {
        // 1) whole-tile fragment loads to registers (retires the buffer)
        short8 bfrag[2][4], afr[2][4];
#pragma unroll
        for (int kk = 0; kk < 2; ++kk) {
#pragma unroll
            for (int ni = 0; ni < 4; ++ni)
                bfrag[kk][ni] = *(const short8*)&SB[(wn * 64 + ni * 16 + l15) * 64 +
                                                   ((kk * 32 + l4 * 8) ^ rxor)];
#pragma unroll
            for (int q = 0; q < 4; ++q)
                afr[kk][q] = *(const short8*)&SA[(wm * 64 + q * 16 + l15) * 64 +
                                                ((kk * 32 + l4 * 8) ^ rxor)];
        }
        asm volatile("s_waitcnt lgkmcnt(0)" ::: "memory");
        bar();                         // all waves done reading -> buffer writable

        // 2) stage next tile into the SAME buffer (DMA lands under the MFMAs)
        if (t + 1 < NT) stage_tile(t + 1);

        // 3) MFMA from registers
        __builtin_amdgcn_s_setprio(1);
#pragma unroll
        for (int kk = 0; kk < 2; ++kk)
#pragma unroll
            for (int q = 0; q < 4; ++q)
#pragma unroll
                for (int ni = 0; ni < 4; ++ni)
                    acc[q][ni] = __builtin_amdgcn_mfma_f32_16x16x32_bf16(
                        afr[kk][q], bfrag[kk][ni], acc[q][ni], 0, 0, 0);
        __builtin_amdgcn_s_setprio(0);

        // 4) next tile landed (slack = the whole MFMA block)
        asm volatile("s_waitcnt vmcnt(0)" ::: "memory");
        bar();
    }

    // epilogue
#pragma unroll
    for (int mi = 0; mi < 4; ++mi) {
#pragma unroll
        for (int ni = 0; ni < 4; ++ni) {
            const int ncol = tileN + wn * 64 + ni * 16 + l15;
            const float bv = bias[ncol];
            const int m0 = tileM + wm * 64 + mi * 16 + l4 * 4;
            if (MODE == 0) {
                const int b_ = m0 >> 11, s0 = m0 & (S - 1);
                const int which = ncol >> 11;
                const int hh = (ncol >> 7) & (H - 1);
                const int hd = ncol & (HD - 1);
                const int bh = b_ * H + hh;
                if (which == 2) {
                    sv4 pk;
#pragma unroll
                    for (int r = 0; r < 4; ++r) {
                        __hip_bfloat16 t = __float2bfloat16(acc[mi][ni][r] + bv);
                        pk[r] = reinterpret_cast<short&>(t);
                    }
                    *(sv4*)&ovT[((size_t)bh * HD + hd) * S + s0] = pk;
                } else {
                    bf16* dst = which ? ok : oq;
#pragma unroll
                    for (int r = 0; r < 4; ++r)
                        dst[((size_t)bh * S + s0 + r) * HD + hd] =
                            __float2bfloat16(acc[mi][ni][r] + bv);
                }
            } else {
#pragma unroll
                for (int r = 0; r < 4; ++r) {
                    const int m = m0 + r;
                    const int b_ = m >> 11, s_ = m & (S - 1);
                    oOut[((size_t)s_ * B + b_) * D + ncol] = acc[mi][ni][r] + bv;
                }
            }
        }
    }
}

// ---------------- fused LayerNorm (over HD) + RoPE for q and k, in place ----------------
// q is additionally pre-scaled by 1/sqrt(HD) (folded out of the attention kernel).
__global__ __launch_bounds__(256) void ln_rope_kernel(
    bf16* __restrict__ q, bf16* __restrict__ k,
    const float* __restrict__ fc,
    const float* __restrict__ qw, const float* __restrict__ qb,
    const float* __restrict__ kw, const float* __restrict__ kb)
{
    const int tid = threadIdx.x;
    const int w = tid >> 6, l = tid & 63;
    const int row = blockIdx.x * 4 + w;      // bh*S + s, 0..65535
    const int s_ = row & (S - 1);
    const size_t base = (size_t)row * HD;
    const float f0 = fc[s_ * HD + 2 * l];
    const float f1 = fc[s_ * HD + 2 * l + 1];

#pragma unroll
    for (int which = 0; which < 2; ++which) {
        bf16* p = which == 0 ? q : k;
        const float* gw = which == 0 ? qw : kw;
        const float* gb = which == 0 ? qb : kb;
        const float osc = which == 0 ? 0.08838834764831845f : 1.0f;  // 1/sqrt(128) on q
        float x0 = __bfloat162float(p[base + 2 * l]);
        float x1 = __bfloat162float(p[base + 2 * l + 1]);
        float sm = x0 + x1;
#pragma unroll
        for (int msk = 1; msk < 64; msk <<= 1) sm += __shfl_xor(sm, msk);
        const float mu = sm * (1.0f / HD);
        const float d0 = x0 - mu, d1 = x1 - mu;
        float vs = d0 * d0 + d1 * d1;
#pragma unroll
        for (int msk = 1; msk < 64; msk <<= 1) vs += __shfl_xor(vs, msk);
        const float rstd = rsqrtf(vs * (1.0f / HD) + 1e-5f);
        const float n0 = d0 * rstd * gw[2 * l] + gb[2 * l];
        const float n1 = d1 * rstd * gw[2 * l + 1] + gb[2 * l + 1];
        p[base + 2 * l]     = __float2bfloat16((n0 * f0 - n1 * f1) * osc);
        p[base + 2 * l + 1] = __float2bfloat16((n1 * f0 + n0 * f1) * osc);
    }
}

// ---------------- causal flash attention: dual-Q pairing + fixed-shift softmax ----------------
// 512 blocks (2/CU exactly): block owns q-tiles (31-pr) and (pr) of one head -> every
// block does exactly 33 tile-works (perfect balance). K/V tiles staged ONCE serve both
// q-tiles over their overlapping KV range. Counted-vmcnt pipeline, K/V double-buffered.
// Per-q-tile QK^T/softmax kept SEQUENTIAL with scoped sacc (merged version spills regs).
// T5: setprio(1) around MFMA clusters (2 independent blocks/CU -> role diversity).
__global__ __launch_bounds__(256, 2) void attn_kernel(
    const bf16* __restrict__ q, const bf16* __restrict__ k, const bf16* __restrict__ vT,
    bf16* __restrict__ out)
{
    __shared__ __align__(16) bf16 KT[2][64 * 128];   // 2 x 16 KB
    __shared__ __align__(16) bf16 VS[2][128 * 64];   // 2 x 16 KB
    __shared__ __align__(16) bf16 Pb[4][16 * 72];    // per-wave P transpose (A then B, sequential)

    const int tid = threadIdx.x, w = tid >> 6, l = tid & 63;
    const int l15 = l & 15, l4 = l >> 4;

    const int id  = blockIdx.y * gridDim.x + blockIdx.x;   // 0..511
    const int nid = (id & 7) * 64 + (id >> 3);             // XCD-chunked (512 % 8 == 0)
    const int bh  = nid >> 4;                               // 0..31
    const int pr  = nid & 15;                               // 0..15
    const int qtA = 31 - pr;                                // heavy q-tile (16..31)
    const int qtB = pr;                                     // light q-tile (0..15)

    const int b_ = bh >> 4, hh = bh & (H - 1);
    const int qrA = qtA * 64 + w * 16;
    const int qrB = qtB * 64 + w * 16;
    const size_t hQ = (size_t)bh * S * HD;
    const size_t hV = (size_t)bh * HD * S;

    const char* kbase = (const char*)(k + hQ);
    const char* vbase = (const char*)(vT + hV);
    int ksrc[4], vsrc[4], kdst[4], vdst[4];
#pragma unroll
    for (int j = 0; j < 4; ++j) {
        const int ik = w * 4 + j;
        const int rt = ik * 4 + (l >> 4);            // K tile row 0..63
        ksrc[j] = rt * 256 + (((l & 15) * 16) ^ ((rt & 15) << 4));
        kdst[j] = ik * 1024;
        const int rd = ik * 8 + (l >> 3);            // V tile row (d) 0..127
        vsrc[j] = rd * (S * 2) + (((l & 7) * 16) ^ ((rd & 7) << 4));
        vdst[j] = ik * 1024;
    }

    short8 aqA[4], aqB[4];
#pragma unroll
    for (int c = 0; c < 4; ++c) {
        aqA[c] = *(const short8*)&q[hQ + (size_t)(qrA + l15) * HD + c * 32 + l4 * 8];
        aqB[c] = *(const short8*)&q[hQ + (size_t)(qrB + l15) * HD + c * 32 + l4 * 8];
    }

    f32x4 oA[8] = {}, oB[8] = {};
    float psA[4] = {0.f, 0.f, 0.f, 0.f}, psB[4] = {0.f, 0.f, 0.f, 0.f};

    // prologue: issue K tile 0 (first iter's vmcnt covers it)
#pragma unroll
    for (int j = 0; j < 4; ++j)
        gload16(kbase + ksrc[j], (char*)KT[0] + kdst[j]);

    const int kx = l15 << 3;          // K read xor (elems): (row&15)<<3
    const int vx = (l15 & 7) << 3;    // V read xor (elems): (row&7)<<3
    const float LOG2E = 1.4426950408889634f;
    const float SHIFT = -23.083120654223414f;   // -16 * log2(e)

    for (int kvt = 0; kvt <= qtA; ++kvt) {
        const int kvb = kvt * 64;
        const int cur = kvt & 1;
        const bool doB = (kvt <= qtB);
        // issue V_t FIRST (pre-PV vmcnt(4) then leaves only K_{t+1} in flight)
#pragma unroll
        for (int j = 0; j < 4; ++j)
            gload16(vbase + (size_t)kvb * 2 + vsrc[j], (char*)VS[cur] + vdst[j]);
        if (kvt < qtA) {
#pragma unroll
            for (int j = 0; j < 4; ++j)
                gload16(kbase + (size_t)(kvb + 64) * 256 + ksrc[j], (char*)KT[cur ^ 1] + kdst[j]);
        }
        // K_t landed for every wave; V_t (+K_{t+1}) stay in flight
        if (kvt < qtA) { asm volatile("s_waitcnt vmcnt(8)" ::: "memory"); }
        else           { asm volatile("s_waitcnt vmcnt(4)" ::: "memory"); }
        bar();

        // ---- q-tile A: QK^T + fixed-shift softmax + P transpose (scoped sacc) ----
        short8 apA[2], apB[2];
        {
            f32x4 sacc[4] = {};
            __builtin_amdgcn_s_setprio(1);
#pragma unroll
            for (int c = 0; c < 4; ++c) {
                const int cole = (c * 32 + l4 * 8) ^ kx;
#pragma unroll
                for (int n = 0; n < 4; ++n) {
                    short8 bk = *(const short8*)&KT[cur][(n * 16 + l15) * 128 + cole];
                    sacc[n] = __builtin_amdgcn_mfma_f32_16x16x32_bf16(aqA[c], bk, sacc[n], 0, 0, 0);
                }
            }
            __builtin_amdgcn_s_setprio(0);
            if (kvt == qtA) {
#pragma unroll
                for (int n = 0; n < 4; ++n)
#pragma unroll
                    for (int r = 0; r < 4; ++r) {
                        float sv = (kvb + n * 16 + l15 > qrA + l4 * 4 + r) ? -1e30f : sacc[n][r];
                        const float pv = __builtin_amdgcn_exp2f(__builtin_fmaf(sv, LOG2E, SHIFT));
                        sacc[n][r] = pv; psA[r] += pv;
                    }
            } else {
#pragma unroll
                for (int n = 0; n < 4; ++n)
#pragma unroll
                    for (int r = 0; r < 4; ++r) {
                        const float pv = __builtin_amdgcn_exp2f(__builtin_fmaf(sacc[n][r], LOG2E, SHIFT));
                        sacc[n][r] = pv; psA[r] += pv;
                    }
            }
#pragma unroll
            for (int n = 0; n < 4; ++n)
#pragma unroll
                for (int r = 0; r < 4; ++r)
                    Pb[w][(l4 * 4 + r) * 72 + n * 16 + l15] = __float2bfloat16(sacc[n][r]);
#pragma unroll
            for (int c = 0; c < 2; ++c)
                apA[c] = *(const short8*)&Pb[w][l15 * 72 + c * 32 + l4 * 8];
        }
        // ---- q-tile B (shares KT[cur]; same-wave sequential Pb reuse) ----
        if (doB) {
            f32x4 sacc[4] = {};
            __builtin_amdgcn_s_setprio(1);
#pragma unroll
            for (int c = 0; c < 4; ++c) {
                const int cole = (c * 32 + l4 * 8) ^ kx;
#pragma unroll
                for (int n = 0; n < 4; ++n) {
                    short8 bk = *(const short8*)&KT[cur][(n * 16 + l15) * 128 + cole];
                    sacc[n] = __builtin_amdgcn_mfma_f32_16x16x32_bf16(aqB[c], bk, sacc[n], 0, 0, 0);
                }
            }
            __builtin_amdgcn_s_setprio(0);
            if (kvt == qtB) {
#pragma unroll
                for (int n = 0; n < 4; ++n)
#pragma unroll
                    for (int r = 0; r < 4; ++r) {
                        float sv = (kvb + n * 16 + l15 > qrB + l4 * 4 + r) ? -1e30f : sacc[n][r];
                        const float pv = __builtin_amdgcn_exp2f(__builtin_fmaf(sv, LOG2E, SHIFT));
                        sacc[n][r] = pv; psB[r] += pv;
                    }
            } else {
#pragma unroll
                for (int n = 0; n < 4; ++n)
#pragma unroll
                    for (int r = 0; r < 4; ++r) {
                        const float pv = __builtin_amdgcn_exp2f(__builtin_fmaf(sacc[n][r], LOG2E, SHIFT));
                        sacc[n][r] = pv; psB[r] += pv;
                    }
            }
#pragma unroll
            for (int n = 0; n < 4; ++n)
#pragma unroll
                for (int r = 0; r < 4; ++r)
                    Pb[w][(l4 * 4 + r) * 72 + n * 16 + l15] = __float2bfloat16(sacc[n][r]);
#pragma unroll
            for (int c = 0; c < 2; ++c)
                apB[c] = *(const short8*)&Pb[w][l15 * 72 + c * 32 + l4 * 8];
        }

        // V_t landed for every wave; K_{t+1} stays in flight
        if (kvt < qtA) { asm volatile("s_waitcnt vmcnt(4)" ::: "memory"); }
        else           { asm volatile("s_waitcnt vmcnt(0)" ::: "memory"); }
        bar();

        __builtin_amdgcn_s_setprio(1);
#pragma unroll
        for (int c = 0; c < 2; ++c) {
#pragma unroll
            for (int d = 0; d < 8; ++d) {
                const int rd = d * 16 + l15;
                short8 bv = *(const short8*)&VS[cur][rd * 64 + ((c * 32 + l4 * 8) ^ vx)];
                oA[d] = __builtin_amdgcn_mfma_f32_16x16x32_bf16(apA[c], bv, oA[d], 0, 0, 0);
            }
        }
        if (doB) {
#pragma unroll
            for (int c = 0; c < 2; ++c) {
#pragma unroll
                for (int d = 0; d < 8; ++d) {
                    const int rd = d * 16 + l15;
                    short8 bv = *(const short8*)&VS[cur][rd * 64 + ((c * 32 + l4 * 8) ^ vx)];
                    oB[d] = __builtin_amdgcn_mfma_f32_16x16x32_bf16(apB[c], bv, oB[d], 0, 0, 0);
                }
            }
        }
        __builtin_amdgcn_s_setprio(0);
        // no end barrier: VS double-buffered; KT[cur^1] overwrite at t+1 is safe
        // (QK^T-t reads completed before this iter's 2nd barrier).
    }

    // epilogue: deferred row-sum reduce, normalize, write bf16 [B,S,D] for both q-tiles
#pragma unroll
    for (int r = 0; r < 4; ++r) {
#pragma unroll
        for (int msk = 1; msk < 16; msk <<= 1) psA[r] += __shfl_xor(psA[r], msk);
        const float inv = 1.0f / psA[r];
        const int s_ = qrA + l4 * 4 + r;
        const size_t obase = ((size_t)b_ * S + s_) * D + hh * HD;
#pragma unroll
        for (int d = 0; d < 8; ++d)
            out[obase + d * 16 + l15] = __float2bfloat16(oA[d][r] * inv);
    }
#pragma unroll
    for (int r = 0; r < 4; ++r) {
#pragma unroll
        for (int msk = 1; msk < 16; msk <<= 1) psB[r] += __shfl_xor(psB[r], msk);
        const float inv = 1.0f / psB[r];
        const int s_ = qrB + l4 * 4 + r;
        const size_t obase = ((size_t)b_ * S + s_) * D + hh * HD;
#pragma unroll
        for (int d = 0; d < 8; ++d)
            out[obase + d * 16 + l15] = __float2bfloat16(oB[d][r] * inv);
    }
}

extern "C" void kernel_launch(void* const* d_in, const int* in_sizes, int n_in,
                              void* d_out, int out_size, void* d_ws, size_t ws_size,
                              hipStream_t stream) {
    const float* x      = (const float*)d_in[0];
    const float* fc     = (const float*)d_in[1];
    const float* wqkv_w = (const float*)d_in[2];
    const float* wqkv_b = (const float*)d_in[3];
    const float* wo_w   = (const float*)d_in[4];
    const float* wo_b   = (const float*)d_in[5];
    const float* qn_w   = (const float*)d_in[6];
    const float* qn_b   = (const float*)d_in[7];
    const float* kn_w   = (const float*)d_in[8];
    const float* kn_b   = (const float*)d_in[9];
    float* out = (float*)d_out;
    char* ws = (char*)d_ws;

    bf16* xb = (bf16*)(ws);                    // [B*S][D]
    bf16* w1 = (bf16*)(ws + 16777216);         // [6144][2048]
    bf16* wo = (bf16*)(ws + 41943040);         // [2048][2048]
    bf16* qb = (bf16*)(ws + 50331648);         // [B][H][S][HD]
    bf16* kb = (bf16*)(ws + 67108864);         // [B][H][S][HD]
    bf16* vT = (bf16*)(ws + 83886080);         // [B][H][HD][S]
    bf16* ao = (bf16*)(ws + 100663296);        // [B*S][D]

    cvt_x_kernel<<<(S * B * D) / (256 * 8), 256, 0, stream>>>(x, xb);
    cvt_w_kernel<<<2048, 256, 0, stream>>>(wqkv_w, w1, N3 * D);
    cvt_w_kernel<<<1024, 256, 0, stream>>>(wo_w, wo, D * D);

    gemm128<0><<<dim3(N3 / 128, (B * S) / 128), 256, 0, stream>>>(
        xb, w1, wqkv_b, qb, kb, vT, nullptr);

    ln_rope_kernel<<<(B * H * S) / 4, 256, 0, stream>>>(qb, kb, fc, qn_w, qn_b, kn_w, kn_b);

    attn_kernel<<<dim3(16, B * H), 256, 0, stream>>>(qb, kb, vT, ao);

    gemm128<1><<<dim3(D / 128, (B * S) / 128), 256, 0, stream>>>(
        ao, wo, wo_b, nullptr, nullptr, nullptr, out);
}